// Round 2
// 12606.548 us; speedup vs baseline: 2.6812x; 2.6812x over previous
//
#include <hip/hip_runtime.h>
#include <stdint.h>

#define BB 64
#define LL 512
#define EE 256
#define HH 256
#define HID2 512
#define G4 1024
#define MM (LL*BB)          // 32768
#define CH 128
#define MROWS (CH*BB)       // 8192
#define IMPOSSIBLE_V (-1e4f)

// LDS layout for k_scan (floats):
//   P  (reduce partials): 8 slices, stride PSTRIDE=1284 (R*20 + b, R in [0,64), b in [0,16))
//   Hs (staged h):        base HSBASE=10272, Hs[k][b] at HSBASE + k*20 + b (k in [0,256))
//   hvS (act gather):     reuses Hs region, ul*17 + b
#define PSTRIDE 1284
#define HSBASE 10272
#define S_FLOATS 15392      // 10272 + 256*20 = 61568 B

__device__ __forceinline__ void agent_store_u64(uint64_t* p, uint64_t v){
  __hip_atomic_store(p, v, __ATOMIC_RELAXED, __HIP_MEMORY_SCOPE_AGENT);
}

// ---------------- embed: Xt[e][m] = emb[xs[b][t]][e], m = t*64+b ----------------
__global__ __launch_bounds__(256) void k_embed(const int* __restrict__ xs,
      const float* __restrict__ emb, float* __restrict__ Xt){
  int id = blockIdx.x*256 + threadIdx.x;      // MM*64 threads
  int m  = id & (MM-1);
  int e4 = (id >> 15) << 2;
  int t = m >> 6, b = m & 63;
  int tok = xs[b*LL + t];
  float4 v = *(const float4*)&emb[(size_t)tok*EE + e4];
  Xt[(size_t)(e4+0)*MM + m] = v.x;
  Xt[(size_t)(e4+1)*MM + m] = v.y;
  Xt[(size_t)(e4+2)*MM + m] = v.z;
  Xt[(size_t)(e4+3)*MM + m] = v.w;
}

// ---------------- input GEMM: Gt[dir][j][ml] = sum_k Xt[k][t0*64+ml]*W[dir][j][k] + bias ----
// grid (64, 16, 2), block 256
__global__ __launch_bounds__(256) void k_ingemm(const float* __restrict__ Xt, int KD,
      const float* __restrict__ W, const float* __restrict__ bias,
      float* __restrict__ G, int t0d0, int t0d1){
  __shared__ float As[32*132];
  __shared__ float Bs[32*68];
  const int tid = threadIdx.x;
  const int m0 = blockIdx.x*128, j0 = blockIdx.y*64, dir = blockIdx.z;
  const int t0 = (dir==0) ? t0d0 : t0d1;
  const float* Wd = W + (size_t)dir*G4*KD;
  const float* Xg = Xt + (size_t)t0*BB;       // column base for this dir's chunk
  float acc[8][4];
  #pragma unroll
  for(int i=0;i<8;i++){
    #pragma unroll
    for(int j=0;j<4;j++) acc[i][j]=0.f;
  }
  const int tx = tid & 15, ty = tid >> 4;
  const int kr = tid >> 3, mq = tid & 7;      // A loader: k-row, m-quad
  const int bj = tid >> 2, bk = (tid & 3)*8;  // B loader
  for(int kt=0; kt<KD; kt+=32){
    #pragma unroll
    for(int i=0;i<4;i++){
      float4 a = *(const float4*)&Xg[(size_t)(kt+kr)*MM + m0 + mq*16 + i*4];
      *(float4*)&As[kr*132 + mq*16 + i*4] = a;
    }
    {
      const float* wp = &Wd[(size_t)(j0 + bj)*KD + kt + bk];
      float4 w0 = *(const float4*)wp;
      float4 w1 = *(const float4*)(wp+4);
      Bs[(bk+0)*68 + bj] = w0.x;
      Bs[(bk+1)*68 + bj] = w0.y;
      Bs[(bk+2)*68 + bj] = w0.z;
      Bs[(bk+3)*68 + bj] = w0.w;
      Bs[(bk+4)*68 + bj] = w1.x;
      Bs[(bk+5)*68 + bj] = w1.y;
      Bs[(bk+6)*68 + bj] = w1.z;
      Bs[(bk+7)*68 + bj] = w1.w;
    }
    __syncthreads();
    #pragma unroll
    for(int k=0;k<32;k++){
      float bq[4], aq[8];
      *(float4*)bq     = *(const float4*)&Bs[k*68 + tx*4];
      *(float4*)aq     = *(const float4*)&As[k*132 + ty*8];
      *(float4*)(aq+4) = *(const float4*)&As[k*132 + ty*8 + 4];
      #pragma unroll
      for(int i=0;i<8;i++){
        #pragma unroll
        for(int j=0;j<4;j++)
          acc[i][j] += aq[i]*bq[j];
      }
    }
    __syncthreads();
  }
  #pragma unroll
  for(int j=0;j<4;j++){
    int jj = j0 + tx*4 + j;
    float bb_ = bias[dir*G4 + jj];
    float* q = &G[((size_t)dir*G4 + jj)*MROWS + m0 + ty*8];
    float4 v0 = {acc[0][j]+bb_, acc[1][j]+bb_, acc[2][j]+bb_, acc[3][j]+bb_};
    float4 v1 = {acc[4][j]+bb_, acc[5][j]+bb_, acc[6][j]+bb_, acc[7][j]+bb_};
    *(float4*)q = v0;
    *(float4*)(q+4) = v1;
  }
}

// ---------------- persistent LSTM scan, one time-chunk, both directions ----------------
// 2-D decomposition: grid dim3(64,2), block 256.
// WG w of dir: unit-group ug = w>>2 (units ug*16..+15), batch-group bg = w&3 (batches bg*16..+15).
// Only the 16 WGs sharing (dir,bg) exchange h: hbuf[par][dir][bg][unit 256][b16] (contiguous
// 16KB block per group) via sc1 (device-scope) read-through loads / write-through stores.
// Flags: one packed 128B line per group (16 producer flags), polled with one dwordx4 sc1 load.
__global__ __launch_bounds__(256,1) void k_scan(const float* __restrict__ G,
      const float* __restrict__ Whh, float* __restrict__ Xout,
      float* __restrict__ hbuf, float* __restrict__ cbuf,
      int* __restrict__ flags, int chunk, int sbase, int first){
  __shared__ float S[S_FLOATS];
  const int dir = blockIdx.y, w = blockIdx.x, tid = threadIdx.x;
  const int ug = w >> 2, bg = w & 3;
  const int u0 = ug*16, b0 = bg*16;
  const int ks = tid & 15, rp = tid >> 4;   // GEMM role: k-slice, row-quad (rows rp*4..+3 of 64)
  const int ul = tid >> 4, bb = tid & 15;   // act role: unit-local, batch-local
  // Wreg[ri][kk] = Whh[dir][g*256 + u0 + (Rl&15)][kk*16 + ks],  Rl = rp*4+ri, g = Rl>>4
  float Wreg[4][16];
  #pragma unroll
  for(int ri=0;ri<4;ri++){
    const int Rl = rp*4 + ri;
    const float* wsrc = &Whh[((size_t)dir*G4 + (Rl>>4)*256 + u0 + (Rl&15))*HH + ks];
    #pragma unroll
    for(int kk=0;kk<16;kk++) Wreg[ri][kk] = wsrc[kk*16];
  }
  float creg = first ? 0.f : cbuf[((size_t)dir*HH + u0+ul)*BB + b0 + bb];
  if(first){
    for(int i=tid;i<5120;i+=256) S[HSBASE + i] = 0.f;   // zero Hs (h0 = 0)
  }
  __syncthreads();

  int* gflag = &flags[(size_t)(dir*4 + bg)*32];

  for(int it=0; it<CH; it++){
    const int sg = sbase + it;
    const int t  = (dir==0) ? (chunk*CH + it) : (LL-1 - chunk*CH - it);
    const int lt = (dir==0) ? it : (CH-1-it);
    // prefetch this thread's 4 gate pre-activations (input GEMM + bias), hidden under poll
    float gp0,gp1,gp2,gp3;
    {
      const float* gb = &G[((size_t)dir*G4 + u0 + ul)*MROWS + (size_t)lt*BB + b0 + bb];
      gp0 = gb[0];
      gp1 = gb[(size_t)256*MROWS];
      gp2 = gb[(size_t)512*MROWS];
      gp3 = gb[(size_t)768*MROWS];
    }
    if(!(first && it==0)){
      if(tid < 4){
        const int4* fp = (const int4*)gflag + tid;
        int spins = 0;
        while(true){
          int4 f;
          asm volatile("global_load_dwordx4 %0, %1, off sc1\n\ts_waitcnt vmcnt(0)"
                       : "=v"(f) : "v"(fp) : "memory");
          if(f.x>=sg && f.y>=sg && f.z>=sg && f.w>=sg) break;
          __builtin_amdgcn_s_sleep(1);
          if(++spins > (1<<22)) break;   // safety valve: never hang
        }
      }
      __syncthreads();
      // stage h: 4 x dwordx4 read-through loads -> padded LDS Hs[k][b] (stride 20)
      const float4* hb4 = (const float4*)&hbuf[(size_t)((((sg+1)&1)*2 + dir)*4 + bg)*4096];
      float4 h0,h1,h2,h3;
      asm volatile("global_load_dwordx4 %0, %1, off sc1" : "=v"(h0) : "v"(hb4 + 0*256 + tid));
      asm volatile("global_load_dwordx4 %0, %1, off sc1" : "=v"(h1) : "v"(hb4 + 1*256 + tid));
      asm volatile("global_load_dwordx4 %0, %1, off sc1" : "=v"(h2) : "v"(hb4 + 2*256 + tid));
      asm volatile("global_load_dwordx4 %0, %1, off sc1" : "=v"(h3) : "v"(hb4 + 3*256 + tid));
      asm volatile("s_waitcnt vmcnt(0)" ::: "memory");
      __builtin_amdgcn_sched_barrier(0);
      {
        const int i0 = 0*256 + tid, i1 = 1*256 + tid, i2 = 2*256 + tid, i3 = 3*256 + tid;
        *(float4*)&S[HSBASE + (i0>>2)*20 + (i0&3)*4] = h0;
        *(float4*)&S[HSBASE + (i1>>2)*20 + (i1&3)*4] = h1;
        *(float4*)&S[HSBASE + (i2>>2)*20 + (i2&3)*4] = h2;
        *(float4*)&S[HSBASE + (i3>>2)*20 + (i3&3)*4] = h3;
      }
      __syncthreads();
    }
    // gate GEMM: acc[ri][bi], k-slice {ks, 16+ks, ..., 240+ks}
    float acc[4][16];
    #pragma unroll
    for(int ri=0;ri<4;ri++){
      #pragma unroll
      for(int bi=0;bi<16;bi++) acc[ri][bi]=0.f;
    }
    {
      const float* hsb = &S[HSBASE + ks*20];
      #pragma unroll
      for(int kk=0;kk<16;kk++){
        float4 ha  = *(const float4*)&hsb[kk*320 + 0];
        float4 hb_ = *(const float4*)&hsb[kk*320 + 4];
        float4 hc  = *(const float4*)&hsb[kk*320 + 8];
        float4 hd  = *(const float4*)&hsb[kk*320 + 12];
        float hq[16] = {ha.x,ha.y,ha.z,ha.w, hb_.x,hb_.y,hb_.z,hb_.w,
                        hc.x,hc.y,hc.z,hc.w, hd.x,hd.y,hd.z,hd.w};
        #pragma unroll
        for(int ri=0;ri<4;ri++){
          const float wv = Wreg[ri][kk];
          #pragma unroll
          for(int bi=0;bi<16;bi++) acc[ri][bi] += wv*hq[bi];
        }
      }
    }
    // reduce over 16 k-slices: phase1 writes slices 0..7, phase2 adds slices 8..15 in place
    if(ks < 8){
      float* pb = &S[(size_t)ks*PSTRIDE + rp*80];
      #pragma unroll
      for(int ri=0;ri<4;ri++){
        #pragma unroll
        for(int bq=0;bq<4;bq++){
          float4 v = {acc[ri][bq*4+0],acc[ri][bq*4+1],acc[ri][bq*4+2],acc[ri][bq*4+3]};
          *(float4*)&pb[ri*20 + bq*4] = v;
        }
      }
    }
    __syncthreads();
    if(ks >= 8){
      float* pb = &S[(size_t)(ks-8)*PSTRIDE + rp*80];
      #pragma unroll
      for(int ri=0;ri<4;ri++){
        #pragma unroll
        for(int bq=0;bq<4;bq++){
          float4 v = *(const float4*)&pb[ri*20 + bq*4];
          v.x += acc[ri][bq*4+0]; v.y += acc[ri][bq*4+1];
          v.z += acc[ri][bq*4+2]; v.w += acc[ri][bq*4+3];
          *(float4*)&pb[ri*20 + bq*4] = v;
        }
      }
    }
    __syncthreads();
    // fused gather + activation: thread (ul, bb) sums its 4 gates over the 8 slices
    float gs0=gp0, gs1=gp1, gs2=gp2, gs3=gp3;
    {
      const float* pb = &S[ul*20 + bb];
      #pragma unroll
      for(int s=0;s<8;s++){
        gs0 += pb[s*PSTRIDE +   0];
        gs1 += pb[s*PSTRIDE + 320];
        gs2 += pb[s*PSTRIDE + 640];
        gs3 += pb[s*PSTRIDE + 960];
      }
    }
    float si = 1.f/(1.f + expf(-gs0));
    float sf = 1.f/(1.f + expf(-gs1));
    float so = 1.f/(1.f + expf(-gs3));
    creg = sf*creg + si*tanhf(gs2);
    float hv = so*tanhf(creg);
    S[HSBASE + ul*17 + bb] = hv;               // hvS gather buffer (Hs region is dead)
    __syncthreads();
    if(tid < 64){
      const int uu = tid>>2, bq = tid&3;
      union { float f[4]; uint64_t u[2]; } hw;
      hw.f[0] = S[HSBASE + uu*17 + bq*4+0];
      hw.f[1] = S[HSBASE + uu*17 + bq*4+1];
      hw.f[2] = S[HSBASE + uu*17 + bq*4+2];
      hw.f[3] = S[HSBASE + uu*17 + bq*4+3];
      uint64_t* hd8 = (uint64_t*)&hbuf[(size_t)(((sg&1)*2 + dir)*4 + bg)*4096]
                      + (size_t)(u0+uu)*8 + bq*2;
      agent_store_u64(hd8,   hw.u[0]);
      agent_store_u64(hd8+1, hw.u[1]);
    }
    asm volatile("s_waitcnt vmcnt(0)" ::: "memory");   // drain wave0's h write-through
    if(tid==0)
      __hip_atomic_store(gflag + ug, sg+1,
                         __ATOMIC_RELAXED, __HIP_MEMORY_SCOPE_AGENT);
    // Xout store off the critical path (after flag)
    Xout[(size_t)(dir*HH + u0+ul)*MM + (size_t)t*BB + b0 + bb] = hv;
  }
  cbuf[((size_t)dir*HH + u0+ul)*BB + b0 + bb] = creg;
}

// ---------------- emissions from Xt: E[m][c] ----------------
__global__ __launch_bounds__(256) void k_emit(const float* __restrict__ Xt,
      const float* __restrict__ Wfc, const float* __restrict__ bfc, float* __restrict__ E){
  __shared__ float Wf[5*512];
  int tid = threadIdx.x;
  for(int i=tid;i<5*512;i+=256) Wf[i] = Wfc[i];
  __syncthreads();
  int m = blockIdx.x*256 + tid;
  float a0=0,a1=0,a2=0,a3=0,a4=0;
  #pragma unroll 4
  for(int k=0;k<512;k++){
    float x = Xt[(size_t)k*MM + m];
    a0 += x*Wf[k]; a1 += x*Wf[512+k]; a2 += x*Wf[1024+k]; a3 += x*Wf[1536+k]; a4 += x*Wf[2048+k];
  }
  float* e = &E[(size_t)m*8];
  e[0]=a0+bfc[0]; e[1]=a1+bfc[1]; e[2]=a2+bfc[2]; e[3]=a3+bfc[3]; e[4]=a4+bfc[4];
}

// ---------------- features: feat[b][t][h] = Xt[h][t*64+b] (tile transpose) ----------------
__global__ __launch_bounds__(256) void k_feat(const float* __restrict__ Xt,
      float* __restrict__ feat){
  __shared__ float T[64][65];
  const int t = blockIdx.y, h0 = blockIdx.x*64;
  const int tid = threadIdx.x;
  const int hr = tid>>2, q = tid&3;
  const float* src = &Xt[(size_t)(h0+hr)*MM + (size_t)t*BB + q*16];
  #pragma unroll
  for(int i=0;i<4;i++){
    float4 v = *(const float4*)&src[i*4];
    T[hr][q*16+i*4+0]=v.x; T[hr][q*16+i*4+1]=v.y;
    T[hr][q*16+i*4+2]=v.z; T[hr][q*16+i*4+3]=v.w;
  }
  __syncthreads();
  float* dst = &feat[((size_t)hr*LL + t)*HID2 + h0 + q*16];
  #pragma unroll
  for(int i=0;i<16;i+=4){
    float4 v = {T[q*16+i+0][hr], T[q*16+i+1][hr], T[q*16+i+2][hr], T[q*16+i+3][hr]};
    *(float4*)&dst[i] = v;
  }
}

__global__ __launch_bounds__(256) void k_mask(float* __restrict__ masks){
  int id = blockIdx.x*256 + threadIdx.x;
  if(id < MM) masks[id] = 1.0f;
}

// ---------------- Viterbi: 1 block, 64 threads, prefetch-pipelined ----------------
__global__ __launch_bounds__(64) void k_viterbi(const float* __restrict__ E,
      const float* __restrict__ trans, float* __restrict__ out_score,
      float* __restrict__ out_tags){
  __shared__ uint16_t bps[LL*BB];
  const int b = threadIdx.x;
  float T[25];
  #pragma unroll
  for(int i=0;i<25;i++) T[i] = trans[i];
  float ms[5];
  #pragma unroll
  for(int c=0;c<5;c++) ms[c] = IMPOSSIBLE_V;
  ms[3] = 0.f;                               // START = 3
  float4 c0 = *(const float4*)&E[(size_t)b*8];
  float  c4 = E[(size_t)b*8 + 4];
  for(int t=0;t<LL;t++){
    float4 n0 = c0; float n4 = c4;
    if(t < LL-1){
      const float* e = &E[(size_t)((t+1)*BB + b)*8];
      n0 = *(const float4*)e; n4 = e[4];
    }
    float ee[5] = {c0.x, c0.y, c0.z, c0.w, c4};
    float ns[5]; int pack = 0;
    #pragma unroll
    for(int to=0;to<5;to++){
      float best = ms[0] + T[to*5+0]; int bi = 0;
      #pragma unroll
      for(int f=1;f<5;f++){
        float v = ms[f] + T[to*5+f];
        if(v > best){ best = v; bi = f; }   // strict > = first-max (jnp.argmax)
      }
      ns[to] = best + ee[to];
      pack |= bi << (3*to);
    }
    bps[t*BB + b] = (uint16_t)pack;
    #pragma unroll
    for(int c=0;c<5;c++) ms[c] = ns[c];
    c0 = n0; c4 = n4;
  }
  float best = ms[0] + T[4*5+0]; int tag = 0; // STOP = 4
  #pragma unroll
  for(int f=1;f<5;f++){
    float v = ms[f] + T[4*5+f];
    if(v > best){ best = v; tag = f; }
  }
  out_score[b] = best;
  out_tags[b*LL + (LL-1)] = (float)tag;
  for(int t=LL-1; t>=1; t--){
    tag = (bps[t*BB + b] >> (3*tag)) & 7;
    out_tags[b*LL + t-1] = (float)tag;
  }
}

extern "C" void kernel_launch(void* const* d_in, const int* in_sizes, int n_in,
                              void* d_out, int out_size, void* d_ws, size_t ws_size,
                              hipStream_t stream){
  const int*   xs    = (const int*)d_in[0];
  const float* emb   = (const float*)d_in[1];
  const float* Wih0  = (const float*)d_in[2];
  const float* Whh0  = (const float*)d_in[3];
  const float* b0    = (const float*)d_in[4];
  const float* WihL  = (const float*)d_in[5];
  const float* WhhL  = (const float*)d_in[6];
  const float* bL    = (const float*)d_in[7];
  const float* Wfc   = (const float*)d_in[8];
  const float* bfc   = (const float*)d_in[9];
  const float* trans = (const float*)d_in[10];

  char* ws = (char*)d_ws;
  int*   flags = (int*)ws;                                   // 8 groups * 128B = 1 KB used
  float* hbuf  = (float*)(ws + 32768);                       // 2par*2dir*4bg*4096 f = 256 KB
  float* cbuf  = (float*)(ws + 32768 + 262144);              // 2*256*64 f32 = 128 KB
  float* Xa    = (float*)(ws + (size_t)(1<<20));                             // 64 MB
  float* Xb    = (float*)(ws + (size_t)(1<<20) + ((size_t)MM*HID2*4));       // 64 MB
  float* G     = (float*)(ws + (size_t)(1<<20) + 2*((size_t)MM*HID2*4));     // 64 MB
  float* emitb = G;                                          // alias: G dead after scans

  (void)hipMemsetAsync(flags, 0, 8192, stream);
  k_embed<<<8192, 256, 0, stream>>>(xs, emb, Xa);
  float* cur = Xa; float* nxt = Xb;
  for(int l=0;l<4;l++){
    int KD = (l==0) ? 256 : 512;
    const float* Wih = (l==0) ? Wih0 : WihL + (size_t)(l-1)*2*G4*HID2;
    const float* Whh = (l==0) ? Whh0 : WhhL + (size_t)(l-1)*2*G4*HH;
    const float* bb  = (l==0) ? b0   : bL  + (size_t)(l-1)*2*G4;
    for(int chunk=0; chunk<4; chunk++){
      int t0d0 = chunk*CH;
      int t0d1 = (LL-CH) - chunk*CH;
      k_ingemm<<<dim3(MROWS/128, G4/64, 2), 256, 0, stream>>>(cur, KD, Wih, bb, G, t0d0, t0d1);
      k_scan<<<dim3(64, 2), 256, 0, stream>>>(G, Whh, nxt, hbuf, cbuf, flags,
                                              chunk, (l*4+chunk)*CH, chunk==0 ? 1 : 0);
    }
    float* tmp = cur; cur = nxt; nxt = tmp;
  }
  k_emit<<<MM/256, 256, 0, stream>>>(cur, Wfc, bfc, emitb);
  float* out       = (float*)d_out;
  float* out_score = out;
  float* out_tags  = out + 64;
  float* out_feat  = out + 64 + MM;
  float* out_masks = out + 64 + MM + (size_t)MM*HID2;
  k_feat<<<dim3(HID2/64, LL), 256, 0, stream>>>(cur, out_feat);
  k_mask<<<MM/256, 256, 0, stream>>>(out_masks);
  k_viterbi<<<1, 64, 0, stream>>>(emitb, trans, out_score, out_tags);
}